// Round 6
// baseline (604.301 us; speedup 1.0000x reference)
//
#include <hip/hip_runtime.h>
#include <math.h>

#define N_TOK 131072
#define DIM   64
#define QS    8
#define KS    1024
#define CHUNK 64               // codewords per LDS chunk (double-buffered)
#define NCHUNK (QS * KS / CHUNK)   // 128 chunks total across all stages

typedef _Float16 f16x8 __attribute__((ext_vector_type(8)));
typedef float    f32x4 __attribute__((ext_vector_type(4)));

#define AS1C(p) ((const __attribute__((address_space(1))) void*)(p))
#define AS3(p)  ((__attribute__((address_space(3))) void*)(p))

#define RSCALE   2048.0f
#define RISCALE  4.8828125e-4f   // 2^-11

// split fp32 v into f16 limbs: v ~= hi + lo * 2^-11
#define SPLIT(v, hi, lo) { _Float16 _h = (_Float16)(v); (hi) = _h; \
                           (lo) = (_Float16)(((v) - (float)_h) * RSCALE); }

// ---- pre-pass 1: split fp32 codebook into two f16 limbs ----
__global__ void conv_kernel(const float* __restrict__ cb,
                            _Float16* __restrict__ ch, _Float16* __restrict__ cl) {
    int i = blockIdx.x * blockDim.x + threadIdx.x;
    if (i < QS * KS * DIM) {
        float c = cb[i];
        _Float16 hi = (_Float16)c;
        ch[i] = hi;
        cl[i] = (_Float16)((c - (float)hi) * RSCALE);
    }
}

// ---- pre-pass 2: -0.5 * ||c||^2 (exact fp32), injected via MFMA C-operand ----
__global__ void dc2_kernel(const float* __restrict__ cb, float* __restrict__ dc2h) {
    int i = blockIdx.x * blockDim.x + threadIdx.x;
    if (i < QS * KS) {
        const float* c = cb + (size_t)i * DIM;
        float s = 0.f;
#pragma unroll
        for (int d = 0; d < DIM; ++d) s = fmaf(c[d], c[d], s);
        dc2h[i] = -0.5f * s;
    }
}

// ---- main: 4 waves/block, 2 token-tiles (A,B) per wave, residual AS LIMBS,
//      double-buffered LDS chunk pipeline: prefetch c+1 after barrier, compute c.
//      Barrier at top of iter c+1 drains a prefetch that flew for a full compute
//      phase -> latency hidden (vs the old stage->barrier-drain stall).
// argmax of  val = r.c - 0.5*||c||^2   (== argmin of squared distance)
__global__ __launch_bounds__(256, 4)
void rvq_mfma_kernel(const float* __restrict__ x,
                     const float* __restrict__ cbf,
                     const _Float16* __restrict__ chg,
                     const _Float16* __restrict__ clg,
                     const float* __restrict__ dc2h,
                     float* __restrict__ out) {
    __shared__ _Float16 lbuf[2][4][2][2][64][8];  // 32 KB [buf][nn][half][limb][lane][8]
    __shared__ float    ldc2[2][CHUNK];           // 512 B  -||c||^2/2, double-buffered
    __shared__ int      idxLDS[4][32];            // 512 B  per-wave argmin broadcast

    const int tid  = threadIdx.x;
    const int wave = tid >> 6;
    const int lane = tid & 63;
    const int quad = lane >> 4;      // A frag: k-group; C/D: row-group
    const int m    = lane & 15;      // A frag: token row; B frag / C-D col: codeword

    const int tokenBase = blockIdx.x * 128 + wave * 32;   // tiles A,B of 16 tokens

    // residual limbs, A-frag layout: frag 0 -> dims quad*8+0..7, frag 1 -> dims 32+quad*8+0..7
    f16x8 ahA0, ahA1, alA0, alA1, ahB0, ahB1, alB0, alB1;
    {
        const float* xa = x + (size_t)(tokenBase + m) * DIM + quad * 8;
        const float* xb = x + (size_t)(tokenBase + 16 + m) * DIM + quad * 8;
        f32x4 a0 = __builtin_nontemporal_load((const f32x4*)(xa));
        f32x4 a1 = __builtin_nontemporal_load((const f32x4*)(xa + 4));
        f32x4 a2 = __builtin_nontemporal_load((const f32x4*)(xa + 32));
        f32x4 a3 = __builtin_nontemporal_load((const f32x4*)(xa + 36));
        f32x4 b0 = __builtin_nontemporal_load((const f32x4*)(xb));
        f32x4 b1 = __builtin_nontemporal_load((const f32x4*)(xb + 4));
        f32x4 b2 = __builtin_nontemporal_load((const f32x4*)(xb + 32));
        f32x4 b3 = __builtin_nontemporal_load((const f32x4*)(xb + 36));
#pragma unroll
        for (int j = 0; j < 4; ++j) {
            SPLIT(a0[j], ahA0[j],   alA0[j]);   SPLIT(a1[j], ahA0[j+4], alA0[j+4]);
            SPLIT(a2[j], ahA1[j],   alA1[j]);   SPLIT(a3[j], ahA1[j+4], alA1[j+4]);
            SPLIT(b0[j], ahB0[j],   alB0[j]);   SPLIT(b1[j], ahB0[j+4], alB0[j+4]);
            SPLIT(b2[j], ahB1[j],   alB1[j]);   SPLIT(b3[j], ahB1[j+4], alB1[j+4]);
        }
    }

    // prefetch of global chunk index c (c = q*16 + cc): wave w stages its nn=w slice
#define PREFETCH(cnext) {                                                          \
        const int _qq = (cnext) >> 4;                                              \
        const int _kk = ((cnext) & 15) * CHUNK;                                    \
        const int _nb = (cnext) & 1;                                               \
        const _Float16* _chq = chg + (size_t)_qq * KS * DIM;                       \
        const _Float16* _clq = clg + (size_t)_qq * KS * DIM;                       \
        const size_t _goff = (size_t)(_kk + wave * 16 + m) * DIM + quad * 8;       \
        __builtin_amdgcn_global_load_lds(AS1C(_chq + _goff),                       \
            AS3(&lbuf[_nb][wave][0][0][0][0]), 16, 0, 0);                          \
        __builtin_amdgcn_global_load_lds(AS1C(_chq + _goff + 32),                  \
            AS3(&lbuf[_nb][wave][1][0][0][0]), 16, 0, 0);                          \
        __builtin_amdgcn_global_load_lds(AS1C(_clq + _goff),                       \
            AS3(&lbuf[_nb][wave][0][1][0][0]), 16, 0, 0);                          \
        __builtin_amdgcn_global_load_lds(AS1C(_clq + _goff + 32),                  \
            AS3(&lbuf[_nb][wave][1][1][0][0]), 16, 0, 0);                          \
        if (tid < CHUNK) ldc2[_nb][tid] = dc2h[_qq * KS + _kk + tid];              \
    }

    PREFETCH(0);

    for (int q = 0; q < QS; ++q) {
        const float* cfq = cbf + (size_t)q * KS * DIM;

        float bvA[4], bvB[4];
        int   biA[4], biB[4];
#pragma unroll
        for (int i = 0; i < 4; ++i) {
            bvA[i] = -INFINITY; bvB[i] = -INFINITY; biA[i] = 0; biB[i] = 0;
        }

        for (int cc = 0; cc < 16; ++cc) {
            const int c = q * 16 + cc;
            __syncthreads();                 // drains prefetch(c) (in flight a full
                                             // compute phase) + protects buf reuse
            if (c + 1 < NCHUNK) PREFETCH(c + 1);

            const int cbuf = c & 1;
            const int k0   = cc * CHUNK;
#pragma unroll 2
            for (int nn = 0; nn < CHUNK / 16; ++nn) {
                f16x8 bh0 = *(const f16x8*)&lbuf[cbuf][nn][0][0][lane][0];
                f16x8 bh1 = *(const f16x8*)&lbuf[cbuf][nn][1][0][lane][0];
                f16x8 bl0 = *(const f16x8*)&lbuf[cbuf][nn][0][1][lane][0];
                f16x8 bl1 = *(const f16x8*)&lbuf[cbuf][nn][1][1][lane][0];
                const float mdv = ldc2[cbuf][nn * 16 + m];   // -||c||^2/2 this col
                const int  cidx = k0 + nn * 16 + m;
                const f32x4 ci   = {mdv, mdv, mdv, mdv};
                const f32x4 zero = {0.f, 0.f, 0.f, 0.f};

                f32x4 hhA = __builtin_amdgcn_mfma_f32_16x16x32_f16(ahA0, bh0, ci, 0, 0, 0);
                f32x4 hhB = __builtin_amdgcn_mfma_f32_16x16x32_f16(ahB0, bh0, ci, 0, 0, 0);
                f32x4 txA = __builtin_amdgcn_mfma_f32_16x16x32_f16(alA0, bh0, zero, 0, 0, 0);
                f32x4 txB = __builtin_amdgcn_mfma_f32_16x16x32_f16(alB0, bh0, zero, 0, 0, 0);
                hhA = __builtin_amdgcn_mfma_f32_16x16x32_f16(ahA1, bh1, hhA, 0, 0, 0);
                hhB = __builtin_amdgcn_mfma_f32_16x16x32_f16(ahB1, bh1, hhB, 0, 0, 0);
                txA = __builtin_amdgcn_mfma_f32_16x16x32_f16(alA1, bh1, txA, 0, 0, 0);
                txB = __builtin_amdgcn_mfma_f32_16x16x32_f16(alB1, bh1, txB, 0, 0, 0);
                txA = __builtin_amdgcn_mfma_f32_16x16x32_f16(ahA0, bl0, txA, 0, 0, 0);
                txB = __builtin_amdgcn_mfma_f32_16x16x32_f16(ahB0, bl0, txB, 0, 0, 0);
                txA = __builtin_amdgcn_mfma_f32_16x16x32_f16(ahA1, bl1, txA, 0, 0, 0);
                txB = __builtin_amdgcn_mfma_f32_16x16x32_f16(ahB1, bl1, txB, 0, 0, 0);
#pragma unroll
                for (int i = 0; i < 4; ++i) {
                    float vA = fmaf(RISCALE, txA[i], hhA[i]);
                    float vB = fmaf(RISCALE, txB[i], hhB[i]);
                    if (vA > bvA[i]) { bvA[i] = vA; biA[i] = cidx; }
                    if (vB > bvB[i]) { bvB[i] = vB; biB[i] = cidx; }
                }
            }
        }

        // cross-lane argmax over 16 cols (tie-break: lowest index == argmin semantics)
#pragma unroll
        for (int mask = 1; mask <= 8; mask <<= 1) {
#pragma unroll
            for (int i = 0; i < 4; ++i) {
                float ovA = __shfl_xor(bvA[i], mask, 64);
                int   oiA = __shfl_xor(biA[i], mask, 64);
                if (ovA > bvA[i] || (ovA == bvA[i] && oiA < biA[i])) { bvA[i] = ovA; biA[i] = oiA; }
                float ovB = __shfl_xor(bvB[i], mask, 64);
                int   oiB = __shfl_xor(biB[i], mask, 64);
                if (ovB > bvB[i] || (ovB == bvB[i] && oiB < biB[i])) { bvB[i] = ovB; biB[i] = oiB; }
            }
        }

        // writer lanes: indices to global + per-wave LDS broadcast (same-wave -> no barrier)
        if (m == 0) {
            float* idxq = out + (size_t)N_TOK * DIM + q;
#pragma unroll
            for (int i = 0; i < 4; ++i) {
                const int rowA = quad * 4 + i;
                idxq[(size_t)(tokenBase + rowA) * QS]      = (float)biA[i];
                idxq[(size_t)(tokenBase + 16 + rowA) * QS] = (float)biB[i];
                idxLDS[wave][rowA]      = biA[i];
                idxLDS[wave][16 + rowA] = biB[i];
            }
        }
        const int idA = idxLDS[wave][m];
        const int idB = idxLDS[wave][16 + m];

        // residual update: reconstruct r from limbs, subtract fp32 codeword, re-split
        float ls = 0.f;
        {
            const float* cp = cfq + (size_t)idA * DIM + quad * 8;
            f32x4 c0 = *(const f32x4*)(cp);
            f32x4 c1 = *(const f32x4*)(cp + 4);
            f32x4 c2 = *(const f32x4*)(cp + 32);
            f32x4 c3 = *(const f32x4*)(cp + 36);
#pragma unroll
            for (int j = 0; j < 4; ++j) {
                float v0 = fmaf(RISCALE, (float)alA0[j],   (float)ahA0[j])   - c0[j];
                float v1 = fmaf(RISCALE, (float)alA0[j+4], (float)ahA0[j+4]) - c1[j];
                float v2 = fmaf(RISCALE, (float)alA1[j],   (float)ahA1[j])   - c2[j];
                float v3 = fmaf(RISCALE, (float)alA1[j+4], (float)ahA1[j+4]) - c3[j];
                ls = fmaf(v0, v0, ls); ls = fmaf(v1, v1, ls);
                ls = fmaf(v2, v2, ls); ls = fmaf(v3, v3, ls);
                SPLIT(v0, ahA0[j],   alA0[j]);   SPLIT(v1, ahA0[j+4], alA0[j+4]);
                SPLIT(v2, ahA1[j],   alA1[j]);   SPLIT(v3, ahA1[j+4], alA1[j+4]);
            }
        }
        {
            const float* cp = cfq + (size_t)idB * DIM + quad * 8;
            f32x4 c0 = *(const f32x4*)(cp);
            f32x4 c1 = *(const f32x4*)(cp + 4);
            f32x4 c2 = *(const f32x4*)(cp + 32);
            f32x4 c3 = *(const f32x4*)(cp + 36);
#pragma unroll
            for (int j = 0; j < 4; ++j) {
                float v0 = fmaf(RISCALE, (float)alB0[j],   (float)ahB0[j])   - c0[j];
                float v1 = fmaf(RISCALE, (float)alB0[j+4], (float)ahB0[j+4]) - c1[j];
                float v2 = fmaf(RISCALE, (float)alB1[j],   (float)ahB1[j])   - c2[j];
                float v3 = fmaf(RISCALE, (float)alB1[j+4], (float)ahB1[j+4]) - c3[j];
                ls = fmaf(v0, v0, ls); ls = fmaf(v1, v1, ls);
                ls = fmaf(v2, v2, ls); ls = fmaf(v3, v3, ls);
                SPLIT(v0, ahB0[j],   alB0[j]);   SPLIT(v1, ahB0[j+4], alB0[j+4]);
                SPLIT(v2, ahB1[j],   alB1[j]);   SPLIT(v3, ahB1[j+4], alB1[j+4]);
            }
        }
#pragma unroll
        for (int mask = 1; mask <= 32; mask <<= 1) ls += __shfl_xor(ls, mask, 64);
        if (lane == 0)
            atomicAdd(out + (size_t)N_TOK * DIM + (size_t)N_TOK * QS + q,
                      ls * (1.0f / ((float)N_TOK * (float)DIM)));
    }

    // xq = x - r_final (reconstruct final residual from limbs)
    {
        const size_t ra = (size_t)(tokenBase + m) * DIM + quad * 8;
        const size_t rb = (size_t)(tokenBase + 16 + m) * DIM + quad * 8;
        f32x4 a0 = __builtin_nontemporal_load((const f32x4*)(x + ra));
        f32x4 a1 = __builtin_nontemporal_load((const f32x4*)(x + ra + 4));
        f32x4 a2 = __builtin_nontemporal_load((const f32x4*)(x + ra + 32));
        f32x4 a3 = __builtin_nontemporal_load((const f32x4*)(x + ra + 36));
        f32x4 b0 = __builtin_nontemporal_load((const f32x4*)(x + rb));
        f32x4 b1 = __builtin_nontemporal_load((const f32x4*)(x + rb + 4));
        f32x4 b2 = __builtin_nontemporal_load((const f32x4*)(x + rb + 32));
        f32x4 b3 = __builtin_nontemporal_load((const f32x4*)(x + rb + 36));
#pragma unroll
        for (int j = 0; j < 4; ++j) {
            a0[j] -= fmaf(RISCALE, (float)alA0[j],   (float)ahA0[j]);
            a1[j] -= fmaf(RISCALE, (float)alA0[j+4], (float)ahA0[j+4]);
            a2[j] -= fmaf(RISCALE, (float)alA1[j],   (float)ahA1[j]);
            a3[j] -= fmaf(RISCALE, (float)alA1[j+4], (float)ahA1[j+4]);
            b0[j] -= fmaf(RISCALE, (float)alB0[j],   (float)ahB0[j]);
            b1[j] -= fmaf(RISCALE, (float)alB0[j+4], (float)ahB0[j+4]);
            b2[j] -= fmaf(RISCALE, (float)alB1[j],   (float)ahB1[j]);
            b3[j] -= fmaf(RISCALE, (float)alB1[j+4], (float)ahB1[j+4]);
        }
        __builtin_nontemporal_store(a0, (f32x4*)(out + ra));
        __builtin_nontemporal_store(a1, (f32x4*)(out + ra + 4));
        __builtin_nontemporal_store(a2, (f32x4*)(out + ra + 32));
        __builtin_nontemporal_store(a3, (f32x4*)(out + ra + 36));
        __builtin_nontemporal_store(b0, (f32x4*)(out + rb));
        __builtin_nontemporal_store(b1, (f32x4*)(out + rb + 4));
        __builtin_nontemporal_store(b2, (f32x4*)(out + rb + 32));
        __builtin_nontemporal_store(b3, (f32x4*)(out + rb + 36));
    }
}

extern "C" void kernel_launch(void* const* d_in, const int* in_sizes, int n_in,
                              void* d_out, int out_size, void* d_ws, size_t ws_size,
                              hipStream_t stream) {
    const float* x   = (const float*)d_in[0];   // (N, D)
    const float* cb  = (const float*)d_in[1];   // (Q, K, D)
    float*       out = (float*)d_out;           // [xq | indices | losses]
    char*        ws  = (char*)d_ws;

    _Float16* ch   = (_Float16*)ws;                       // 1 MB
    _Float16* cl   = (_Float16*)(ws + 1048576);           // 1 MB
    float*    dc2h = (float*)(ws + 2097152);              // 32 KB

    hipMemsetAsync(out + (size_t)N_TOK * DIM + (size_t)N_TOK * QS, 0,
                   QS * sizeof(float), stream);

    conv_kernel<<<(QS * KS * DIM + 255) / 256, 256, 0, stream>>>(cb, ch, cl);
    dc2_kernel<<<(QS * KS + 255) / 256, 256, 0, stream>>>(cb, dc2h);
    rvq_mfma_kernel<<<N_TOK / 128, 256, 0, stream>>>(x, cb, ch, cl, dc2h, out);
}

// Round 7
// 592.941 us; speedup vs baseline: 1.0192x; 1.0192x over previous
//
#include <hip/hip_runtime.h>
#include <math.h>

#define N_TOK 131072
#define DIM   64
#define QS    8
#define KS    1024

typedef _Float16 f16x8 __attribute__((ext_vector_type(8)));
typedef float    f32x4 __attribute__((ext_vector_type(4)));

#define RSCALE   2048.0f
#define RISCALE  4.8828125e-4f   // 2^-11

// split fp32 v into f16 limbs: v ~= hi + lo * 2^-11
#define SPLIT(v, hi, lo) { _Float16 _h = (_Float16)(v); (hi) = _h; \
                           (lo) = (_Float16)(((v) - (float)_h) * RSCALE); }

// ---- pre-pass 1: codebook -> f16 limbs in MFMA B-FRAGMENT order ----
// F[slot][lane][j],  slot = ((q*64+g)*2+l)*2+h   (g: 16-cw group, l: limb, h: K-half)
//   = limb_l( cb[q][g*16 + (lane&15)][h*32 + (lane>>4)*8 + j] )
// so the main kernel's B-frag load is: base + lane*16B  (perfectly coalesced 1KB)
__global__ void conv_kernel(const float* __restrict__ cb, _Float16* __restrict__ F) {
    int t = blockIdx.x * blockDim.x + threadIdx.x;
    if (t >= 2048 * 64) return;
    const int lane = t & 63, slot = t >> 6;
    const int h = slot & 1, l = (slot >> 1) & 1, g = (slot >> 2) & 63, q = slot >> 8;
    const int cw = g * 16 + (lane & 15);
    const int d0 = h * 32 + (lane >> 4) * 8;
    const float* src = cb + ((size_t)q * KS + cw) * DIM + d0;
    f16x8 v;
#pragma unroll
    for (int j = 0; j < 8; ++j) {
        float c = src[j];
        _Float16 hi = (_Float16)c;
        v[j] = (l == 0) ? hi : (_Float16)((c - (float)hi) * RSCALE);
    }
    *(f16x8*)(F + (size_t)slot * 512 + lane * 8) = v;
}

// ---- pre-pass 2: -0.5 * ||c||^2 (exact fp32), injected via MFMA C-operand ----
__global__ void dc2_kernel(const float* __restrict__ cb, float* __restrict__ dc2h) {
    int i = blockIdx.x * blockDim.x + threadIdx.x;
    if (i < QS * KS) {
        const float* c = cb + (size_t)i * DIM;
        float s = 0.f;
#pragma unroll
        for (int d = 0; d < DIM; ++d) s = fmaf(c[d], c[d], s);
        dc2h[i] = -0.5f * s;
    }
}

// ---- main: NO LDS staging, NO barriers. B-frags stream from L1/L2 into VGPRs,
//      register double-buffered over 16-codeword groups. Residual as f16 limbs.
// argmax of  val = r.c - 0.5*||c||^2   (== argmin of squared distance)
__global__ __launch_bounds__(256, 4)
void rvq_mfma_kernel(const float* __restrict__ x,
                     const float* __restrict__ cbf,
                     const _Float16* __restrict__ F,
                     const float* __restrict__ dc2h,
                     float* __restrict__ out) {
    __shared__ int idxLDS[4][32];     // per-wave argmin broadcast (same-wave use only)

    const int tid  = threadIdx.x;
    const int wave = tid >> 6;
    const int lane = tid & 63;
    const int quad = lane >> 4;
    const int m    = lane & 15;

    const int tokenBase = blockIdx.x * 128 + wave * 32;   // tiles A,B of 16 tokens

    // residual limbs, A-frag layout
    f16x8 ahA0, ahA1, alA0, alA1, ahB0, ahB1, alB0, alB1;
    {
        const float* xa = x + (size_t)(tokenBase + m) * DIM + quad * 8;
        const float* xb = x + (size_t)(tokenBase + 16 + m) * DIM + quad * 8;
        f32x4 a0 = __builtin_nontemporal_load((const f32x4*)(xa));
        f32x4 a1 = __builtin_nontemporal_load((const f32x4*)(xa + 4));
        f32x4 a2 = __builtin_nontemporal_load((const f32x4*)(xa + 32));
        f32x4 a3 = __builtin_nontemporal_load((const f32x4*)(xa + 36));
        f32x4 b0 = __builtin_nontemporal_load((const f32x4*)(xb));
        f32x4 b1 = __builtin_nontemporal_load((const f32x4*)(xb + 4));
        f32x4 b2 = __builtin_nontemporal_load((const f32x4*)(xb + 32));
        f32x4 b3 = __builtin_nontemporal_load((const f32x4*)(xb + 36));
#pragma unroll
        for (int j = 0; j < 4; ++j) {
            SPLIT(a0[j], ahA0[j],   alA0[j]);   SPLIT(a1[j], ahA0[j+4], alA0[j+4]);
            SPLIT(a2[j], ahA1[j],   alA1[j]);   SPLIT(a3[j], ahA1[j+4], alA1[j+4]);
            SPLIT(b0[j], ahB0[j],   alB0[j]);   SPLIT(b1[j], ahB0[j+4], alB0[j+4]);
            SPLIT(b2[j], ahB1[j],   alB1[j]);   SPLIT(b3[j], ahB1[j+4], alB1[j+4]);
        }
    }

// 12 MFMA + selection for one 16-codeword group using B-regs (BH0,BH1,BL0,BL1)
#define COMPUTE(BH0, BH1, BL0, BL1, MDV, G) {                                        \
        const int cidx = (G) * 16 + m;                                               \
        const f32x4 ci   = {(MDV), (MDV), (MDV), (MDV)};                             \
        const f32x4 zero = {0.f, 0.f, 0.f, 0.f};                                     \
        f32x4 hhA = __builtin_amdgcn_mfma_f32_16x16x32_f16(ahA0, BH0, ci, 0, 0, 0);  \
        f32x4 hhB = __builtin_amdgcn_mfma_f32_16x16x32_f16(ahB0, BH0, ci, 0, 0, 0);  \
        f32x4 txA = __builtin_amdgcn_mfma_f32_16x16x32_f16(alA0, BH0, zero, 0, 0, 0);\
        f32x4 txB = __builtin_amdgcn_mfma_f32_16x16x32_f16(alB0, BH0, zero, 0, 0, 0);\
        hhA = __builtin_amdgcn_mfma_f32_16x16x32_f16(ahA1, BH1, hhA, 0, 0, 0);       \
        hhB = __builtin_amdgcn_mfma_f32_16x16x32_f16(ahB1, BH1, hhB, 0, 0, 0);       \
        txA = __builtin_amdgcn_mfma_f32_16x16x32_f16(alA1, BH1, txA, 0, 0, 0);       \
        txB = __builtin_amdgcn_mfma_f32_16x16x32_f16(alB1, BH1, txB, 0, 0, 0);       \
        txA = __builtin_amdgcn_mfma_f32_16x16x32_f16(ahA0, BL0, txA, 0, 0, 0);       \
        txB = __builtin_amdgcn_mfma_f32_16x16x32_f16(ahB0, BL0, txB, 0, 0, 0);       \
        txA = __builtin_amdgcn_mfma_f32_16x16x32_f16(ahA1, BL1, txA, 0, 0, 0);       \
        txB = __builtin_amdgcn_mfma_f32_16x16x32_f16(ahB1, BL1, txB, 0, 0, 0);       \
        _Pragma("unroll")                                                            \
        for (int i = 0; i < 4; ++i) {                                                \
            float vA = fmaf(RISCALE, txA[i], hhA[i]);                                \
            float vB = fmaf(RISCALE, txB[i], hhB[i]);                                \
            if (vA > bvA[i]) { bvA[i] = vA; biA[i] = cidx; }                         \
            if (vB > bvB[i]) { bvB[i] = vB; biB[i] = cidx; }                         \
        }                                                                            \
    }

    for (int q = 0; q < QS; ++q) {
        // per-stage fragment slab: 64 groups x 4KB; this lane's slice
        const _Float16* Bl  = F + (size_t)q * 64 * 2048 + lane * 8;
        const float*    dq  = dc2h + q * KS;
        const float*    cfq = cbf  + (size_t)q * KS * DIM;

        float bvA[4], bvB[4];
        int   biA[4], biB[4];
#pragma unroll
        for (int i = 0; i < 4; ++i) {
            bvA[i] = -INFINITY; bvB[i] = -INFINITY; biA[i] = 0; biB[i] = 0;
        }

        // register double-buffer over the 64 groups — no barriers anywhere
        f16x8 c0h0 = *(const f16x8*)(Bl);
        f16x8 c0h1 = *(const f16x8*)(Bl + 512);
        f16x8 c0l0 = *(const f16x8*)(Bl + 1024);
        f16x8 c0l1 = *(const f16x8*)(Bl + 1536);
        float mdv0 = dq[m];
        f16x8 c1h0, c1h1, c1l0, c1l1;
        float mdv1;

        for (int g = 0; g < 64; g += 2) {
            {   // prefetch g+1
                const _Float16* p = Bl + (size_t)(g + 1) * 2048;
                c1h0 = *(const f16x8*)(p);
                c1h1 = *(const f16x8*)(p + 512);
                c1l0 = *(const f16x8*)(p + 1024);
                c1l1 = *(const f16x8*)(p + 1536);
                mdv1 = dq[(g + 1) * 16 + m];
            }
            COMPUTE(c0h0, c0h1, c0l0, c0l1, mdv0, g);
            if (g + 2 < 64) {   // prefetch g+2
                const _Float16* p = Bl + (size_t)(g + 2) * 2048;
                c0h0 = *(const f16x8*)(p);
                c0h1 = *(const f16x8*)(p + 512);
                c0l0 = *(const f16x8*)(p + 1024);
                c0l1 = *(const f16x8*)(p + 1536);
                mdv0 = dq[(g + 2) * 16 + m];
            }
            COMPUTE(c1h0, c1h1, c1l0, c1l1, mdv1, g + 1);
        }

        // cross-lane argmax over 16 cols (tie-break: lowest index == argmin semantics)
#pragma unroll
        for (int mask = 1; mask <= 8; mask <<= 1) {
#pragma unroll
            for (int i = 0; i < 4; ++i) {
                float ovA = __shfl_xor(bvA[i], mask, 64);
                int   oiA = __shfl_xor(biA[i], mask, 64);
                if (ovA > bvA[i] || (ovA == bvA[i] && oiA < biA[i])) { bvA[i] = ovA; biA[i] = oiA; }
                float ovB = __shfl_xor(bvB[i], mask, 64);
                int   oiB = __shfl_xor(biB[i], mask, 64);
                if (ovB > bvB[i] || (ovB == bvB[i] && oiB < biB[i])) { bvB[i] = ovB; biB[i] = oiB; }
            }
        }

        // writer lanes: indices to global + per-wave LDS broadcast (same-wave -> no barrier)
        if (m == 0) {
            float* idxq = out + (size_t)N_TOK * DIM + q;
#pragma unroll
            for (int i = 0; i < 4; ++i) {
                const int rowA = quad * 4 + i;
                idxq[(size_t)(tokenBase + rowA) * QS]      = (float)biA[i];
                idxq[(size_t)(tokenBase + 16 + rowA) * QS] = (float)biB[i];
                idxLDS[wave][rowA]      = biA[i];
                idxLDS[wave][16 + rowA] = biB[i];
            }
        }
        const int idA = idxLDS[wave][m];
        const int idB = idxLDS[wave][16 + m];

        // residual update: reconstruct r from limbs, subtract fp32 codeword, re-split
        float ls = 0.f;
        {
            const float* cp = cfq + (size_t)idA * DIM + quad * 8;
            f32x4 c0 = *(const f32x4*)(cp);
            f32x4 c1 = *(const f32x4*)(cp + 4);
            f32x4 c2 = *(const f32x4*)(cp + 32);
            f32x4 c3 = *(const f32x4*)(cp + 36);
#pragma unroll
            for (int j = 0; j < 4; ++j) {
                float v0 = fmaf(RISCALE, (float)alA0[j],   (float)ahA0[j])   - c0[j];
                float v1 = fmaf(RISCALE, (float)alA0[j+4], (float)ahA0[j+4]) - c1[j];
                float v2 = fmaf(RISCALE, (float)alA1[j],   (float)ahA1[j])   - c2[j];
                float v3 = fmaf(RISCALE, (float)alA1[j+4], (float)ahA1[j+4]) - c3[j];
                ls = fmaf(v0, v0, ls); ls = fmaf(v1, v1, ls);
                ls = fmaf(v2, v2, ls); ls = fmaf(v3, v3, ls);
                SPLIT(v0, ahA0[j],   alA0[j]);   SPLIT(v1, ahA0[j+4], alA0[j+4]);
                SPLIT(v2, ahA1[j],   alA1[j]);   SPLIT(v3, ahA1[j+4], alA1[j+4]);
            }
        }
        {
            const float* cp = cfq + (size_t)idB * DIM + quad * 8;
            f32x4 c0 = *(const f32x4*)(cp);
            f32x4 c1 = *(const f32x4*)(cp + 4);
            f32x4 c2 = *(const f32x4*)(cp + 32);
            f32x4 c3 = *(const f32x4*)(cp + 36);
#pragma unroll
            for (int j = 0; j < 4; ++j) {
                float v0 = fmaf(RISCALE, (float)alB0[j],   (float)ahB0[j])   - c0[j];
                float v1 = fmaf(RISCALE, (float)alB0[j+4], (float)ahB0[j+4]) - c1[j];
                float v2 = fmaf(RISCALE, (float)alB1[j],   (float)ahB1[j])   - c2[j];
                float v3 = fmaf(RISCALE, (float)alB1[j+4], (float)ahB1[j+4]) - c3[j];
                ls = fmaf(v0, v0, ls); ls = fmaf(v1, v1, ls);
                ls = fmaf(v2, v2, ls); ls = fmaf(v3, v3, ls);
                SPLIT(v0, ahB0[j],   alB0[j]);   SPLIT(v1, ahB0[j+4], alB0[j+4]);
                SPLIT(v2, ahB1[j],   alB1[j]);   SPLIT(v3, ahB1[j+4], alB1[j+4]);
            }
        }
#pragma unroll
        for (int mask = 1; mask <= 32; mask <<= 1) ls += __shfl_xor(ls, mask, 64);
        if (lane == 0)
            atomicAdd(out + (size_t)N_TOK * DIM + (size_t)N_TOK * QS + q,
                      ls * (1.0f / ((float)N_TOK * (float)DIM)));
    }

    // xq = x - r_final (reconstruct final residual from limbs)
    {
        const size_t ra = (size_t)(tokenBase + m) * DIM + quad * 8;
        const size_t rb = (size_t)(tokenBase + 16 + m) * DIM + quad * 8;
        f32x4 a0 = __builtin_nontemporal_load((const f32x4*)(x + ra));
        f32x4 a1 = __builtin_nontemporal_load((const f32x4*)(x + ra + 4));
        f32x4 a2 = __builtin_nontemporal_load((const f32x4*)(x + ra + 32));
        f32x4 a3 = __builtin_nontemporal_load((const f32x4*)(x + ra + 36));
        f32x4 b0 = __builtin_nontemporal_load((const f32x4*)(x + rb));
        f32x4 b1 = __builtin_nontemporal_load((const f32x4*)(x + rb + 4));
        f32x4 b2 = __builtin_nontemporal_load((const f32x4*)(x + rb + 32));
        f32x4 b3 = __builtin_nontemporal_load((const f32x4*)(x + rb + 36));
#pragma unroll
        for (int j = 0; j < 4; ++j) {
            a0[j] -= fmaf(RISCALE, (float)alA0[j],   (float)ahA0[j]);
            a1[j] -= fmaf(RISCALE, (float)alA0[j+4], (float)ahA0[j+4]);
            a2[j] -= fmaf(RISCALE, (float)alA1[j],   (float)ahA1[j]);
            a3[j] -= fmaf(RISCALE, (float)alA1[j+4], (float)ahA1[j+4]);
            b0[j] -= fmaf(RISCALE, (float)alB0[j],   (float)ahB0[j]);
            b1[j] -= fmaf(RISCALE, (float)alB0[j+4], (float)ahB0[j+4]);
            b2[j] -= fmaf(RISCALE, (float)alB1[j],   (float)ahB1[j]);
            b3[j] -= fmaf(RISCALE, (float)alB1[j+4], (float)ahB1[j+4]);
        }
        __builtin_nontemporal_store(a0, (f32x4*)(out + ra));
        __builtin_nontemporal_store(a1, (f32x4*)(out + ra + 4));
        __builtin_nontemporal_store(a2, (f32x4*)(out + ra + 32));
        __builtin_nontemporal_store(a3, (f32x4*)(out + ra + 36));
        __builtin_nontemporal_store(b0, (f32x4*)(out + rb));
        __builtin_nontemporal_store(b1, (f32x4*)(out + rb + 4));
        __builtin_nontemporal_store(b2, (f32x4*)(out + rb + 32));
        __builtin_nontemporal_store(b3, (f32x4*)(out + rb + 36));
    }
#undef COMPUTE
}

extern "C" void kernel_launch(void* const* d_in, const int* in_sizes, int n_in,
                              void* d_out, int out_size, void* d_ws, size_t ws_size,
                              hipStream_t stream) {
    const float* x   = (const float*)d_in[0];   // (N, D)
    const float* cb  = (const float*)d_in[1];   // (Q, K, D)
    float*       out = (float*)d_out;           // [xq | indices | losses]
    char*        ws  = (char*)d_ws;

    _Float16* F    = (_Float16*)ws;                       // 2 MB fragment-ordered limbs
    float*    dc2h = (float*)(ws + 2097152);              // 32 KB

    hipMemsetAsync(out + (size_t)N_TOK * DIM + (size_t)N_TOK * QS, 0,
                   QS * sizeof(float), stream);

    conv_kernel<<<512, 256, 0, stream>>>(cb, F);
    dc2_kernel<<<(QS * KS + 255) / 256, 256, 0, stream>>>(cb, dc2h);
    rvq_mfma_kernel<<<N_TOK / 128, 256, 0, stream>>>(x, cb, F, dc2h, out);
}

// Round 8
// 584.126 us; speedup vs baseline: 1.0345x; 1.0151x over previous
//
#include <hip/hip_runtime.h>
#include <math.h>

#define N_TOK 131072
#define DIM   64
#define QS    8
#define KS    1024

typedef _Float16 f16x8 __attribute__((ext_vector_type(8)));
typedef float    f32x4 __attribute__((ext_vector_type(4)));

#define RSCALE   2048.0f
#define RISCALE  4.8828125e-4f   // 2^-11

// split fp32 v into f16 limbs + scaled-hi: v ~= hi + lo*2^-11 ; hs = 2048*hi (exact)
#define SPLIT3(v, hi, lo, hs) { _Float16 _h = (_Float16)(v); (hi) = _h;        \
                                (lo) = (_Float16)(((v) - (float)_h) * RSCALE); \
                                (hs) = (_Float16)((float)_h * RSCALE); }

// ---- pre-pass 1: codebook -> f16 limbs in MFMA fragment order (A and B layouts
// share the [idx=lane&15][k=quad*8+j] lane mapping, so F serves as A-frags too).
// F[slot][lane][j], slot = ((q*64+g)*2+l)*2+h  (g: 16-cw group, l: limb, h: K-half)
__global__ void conv_kernel(const float* __restrict__ cb, _Float16* __restrict__ F) {
    int t = blockIdx.x * blockDim.x + threadIdx.x;
    if (t >= 2048 * 64) return;
    const int lane = t & 63, slot = t >> 6;
    const int h = slot & 1, l = (slot >> 1) & 1, g = (slot >> 2) & 63, q = slot >> 8;
    const int cw = g * 16 + (lane & 15);
    const int d0 = h * 32 + (lane >> 4) * 8;
    const float* src = cb + ((size_t)q * KS + cw) * DIM + d0;
    f16x8 v;
#pragma unroll
    for (int j = 0; j < 8; ++j) {
        float c = src[j];
        _Float16 hi = (_Float16)c;
        v[j] = (l == 0) ? hi : (_Float16)((c - (float)hi) * RSCALE);
    }
    *(f16x8*)(F + (size_t)slot * 512 + lane * 8) = v;
}

// ---- pre-pass 2: 2048 * (-||c||^2 / 2) = -1024*||c||^2, seeds the MFMA chain ----
__global__ void dc2_kernel(const float* __restrict__ cb, float* __restrict__ dc2s) {
    int i = blockIdx.x * blockDim.x + threadIdx.x;
    if (i < QS * KS) {
        const float* c = cb + (size_t)i * DIM;
        float s = 0.f;
#pragma unroll
        for (int d = 0; d < DIM; ++d) s = fmaf(c[d], c[d], s);
        dc2s[i] = -1024.0f * s;
    }
}

// ---- main: transposed MFMA (A = codewords from F, B = token limbs).
// Single 6-MFMA chain per tile accumulates 2048*(r.c - ||c||^2/2) directly:
//   ch*(2048 rh) + (2048(c-ch))*rh + ch*(2048(r-rh))  + C=-1024||c||^2
// -> ZERO VALU combine per distance. Per lane: 4 accs = 4 codewords of ONE token.
// No LDS, no barriers anywhere. Register double-buffer over 16-cw groups.
__global__ __launch_bounds__(256, 4)
void rvq_mfma_kernel(const float* __restrict__ x,
                     const float* __restrict__ cbf,
                     const _Float16* __restrict__ F,
                     const float* __restrict__ dc2s,
                     float* __restrict__ out) {
    const int tid  = threadIdx.x;
    const int wave = tid >> 6;
    const int lane = tid & 63;
    const int quad = lane >> 4;
    const int m    = lane & 15;
    const int quad4 = quad * 4;

    const int tokenBase = blockIdx.x * 128 + wave * 32;
    const int tokA = tokenBase + m, tokB = tokenBase + 16 + m;

    // token limbs (B-frag layout): th = hi, tl = 2048*(r-hi), ts = 2048*hi
    f16x8 thA0, thA1, tlA0, tlA1, tsA0, tsA1;
    f16x8 thB0, thB1, tlB0, tlB1, tsB0, tsB1;
    {
        const float* xa = x + (size_t)tokA * DIM + quad * 8;
        const float* xb = x + (size_t)tokB * DIM + quad * 8;
        f32x4 a0 = __builtin_nontemporal_load((const f32x4*)(xa));
        f32x4 a1 = __builtin_nontemporal_load((const f32x4*)(xa + 4));
        f32x4 a2 = __builtin_nontemporal_load((const f32x4*)(xa + 32));
        f32x4 a3 = __builtin_nontemporal_load((const f32x4*)(xa + 36));
        f32x4 b0 = __builtin_nontemporal_load((const f32x4*)(xb));
        f32x4 b1 = __builtin_nontemporal_load((const f32x4*)(xb + 4));
        f32x4 b2 = __builtin_nontemporal_load((const f32x4*)(xb + 32));
        f32x4 b3 = __builtin_nontemporal_load((const f32x4*)(xb + 36));
#pragma unroll
        for (int j = 0; j < 4; ++j) {
            SPLIT3(a0[j], thA0[j],   tlA0[j],   tsA0[j]);
            SPLIT3(a1[j], thA0[j+4], tlA0[j+4], tsA0[j+4]);
            SPLIT3(a2[j], thA1[j],   tlA1[j],   tsA1[j]);
            SPLIT3(a3[j], thA1[j+4], tlA1[j+4], tsA1[j+4]);
            SPLIT3(b0[j], thB0[j],   tlB0[j],   tsB0[j]);
            SPLIT3(b1[j], thB0[j+4], tlB0[j+4], tsB0[j+4]);
            SPLIT3(b2[j], thB1[j],   tlB1[j],   tsB1[j]);
            SPLIT3(b3[j], thB1[j+4], tlB1[j+4], tsB1[j+4]);
        }
    }

// One group: 2 chains of 6 MFMA; acc IS the scaled score, no VALU combine.
#define COMPUTE(CH0, CH1, CL0, CL1, CIV, G) {                                       \
        f32x4 accA = __builtin_amdgcn_mfma_f32_16x16x32_f16(CH0, tsA0, CIV, 0,0,0); \
        f32x4 accB = __builtin_amdgcn_mfma_f32_16x16x32_f16(CH0, tsB0, CIV, 0,0,0); \
        accA = __builtin_amdgcn_mfma_f32_16x16x32_f16(CH1, tsA1, accA, 0,0,0);      \
        accB = __builtin_amdgcn_mfma_f32_16x16x32_f16(CH1, tsB1, accB, 0,0,0);      \
        accA = __builtin_amdgcn_mfma_f32_16x16x32_f16(CL0, thA0, accA, 0,0,0);      \
        accB = __builtin_amdgcn_mfma_f32_16x16x32_f16(CL0, thB0, accB, 0,0,0);      \
        accA = __builtin_amdgcn_mfma_f32_16x16x32_f16(CL1, thA1, accA, 0,0,0);      \
        accB = __builtin_amdgcn_mfma_f32_16x16x32_f16(CL1, thB1, accB, 0,0,0);      \
        accA = __builtin_amdgcn_mfma_f32_16x16x32_f16(CH0, tlA0, accA, 0,0,0);      \
        accB = __builtin_amdgcn_mfma_f32_16x16x32_f16(CH0, tlB0, accB, 0,0,0);      \
        accA = __builtin_amdgcn_mfma_f32_16x16x32_f16(CH1, tlA1, accA, 0,0,0);      \
        accB = __builtin_amdgcn_mfma_f32_16x16x32_f16(CH1, tlB1, accB, 0,0,0);      \
        const int base = (G) * 16 + quad4;                                          \
        _Pragma("unroll")                                                           \
        for (int i = 0; i < 4; ++i) {                                               \
            if (accA[i] > bvA) { bvA = accA[i]; biA = base + i; }                   \
            if (accB[i] > bvB) { bvB = accB[i]; biB = base + i; }                   \
        }                                                                           \
    }

    for (int q = 0; q < QS; ++q) {
        const _Float16* Bl  = F    + (size_t)q * 64 * 2048 + lane * 8;
        const float*    dq  = dc2s + q * KS;
        const float*    cfq = cbf  + (size_t)q * KS * DIM;

        float bvA = -INFINITY, bvB = -INFINITY;
        int   biA = 0,         biB = 0;

        // register double-buffer over the 64 groups — no barriers anywhere
        f16x8 c0h0 = *(const f16x8*)(Bl);
        f16x8 c0h1 = *(const f16x8*)(Bl + 512);
        f16x8 c0l0 = *(const f16x8*)(Bl + 1024);
        f16x8 c0l1 = *(const f16x8*)(Bl + 1536);
        f32x4 ci0  = *(const f32x4*)(dq + quad4);
        f16x8 c1h0, c1h1, c1l0, c1l1;
        f32x4 ci1;

        for (int g = 0; g < 64; g += 2) {
            {   // prefetch g+1
                const _Float16* p = Bl + (size_t)(g + 1) * 2048;
                c1h0 = *(const f16x8*)(p);
                c1h1 = *(const f16x8*)(p + 512);
                c1l0 = *(const f16x8*)(p + 1024);
                c1l1 = *(const f16x8*)(p + 1536);
                ci1  = *(const f32x4*)(dq + (g + 1) * 16 + quad4);
            }
            COMPUTE(c0h0, c0h1, c0l0, c0l1, ci0, g);
            if (g + 2 < 64) {   // prefetch g+2
                const _Float16* p = Bl + (size_t)(g + 2) * 2048;
                c0h0 = *(const f16x8*)(p);
                c0h1 = *(const f16x8*)(p + 512);
                c0l0 = *(const f16x8*)(p + 1024);
                c0l1 = *(const f16x8*)(p + 1536);
                ci0  = *(const f32x4*)(dq + (g + 2) * 16 + quad4);
            }
            COMPUTE(c1h0, c1h1, c1l0, c1l1, ci1, g + 1);
        }

        // reduce over the 4 quad-lanes holding the same token (disjoint codewords):
        // 2 shuffle steps (was 4). Tie-break: lowest index, matching jnp.argmin.
#pragma unroll
        for (int mask = 16; mask <= 32; mask <<= 1) {
            float ovA = __shfl_xor(bvA, mask, 64);
            int   oiA = __shfl_xor(biA, mask, 64);
            if (ovA > bvA || (ovA == bvA && oiA < biA)) { bvA = ovA; biA = oiA; }
            float ovB = __shfl_xor(bvB, mask, 64);
            int   oiB = __shfl_xor(biB, mask, 64);
            if (ovB > bvB || (ovB == bvB && oiB < biB)) { bvB = ovB; biB = oiB; }
        }

        // indices straight to global (every lane already has its token's winner)
        if (quad == 0)      out[(size_t)N_TOK * DIM + (size_t)tokA * QS + q] = (float)biA;
        else if (quad == 1) out[(size_t)N_TOK * DIM + (size_t)tokB * QS + q] = (float)biB;

        // residual update: reconstruct r from limbs, subtract fp32 codeword, re-split
        float ls = 0.f;
        {
            const float* cp = cfq + (size_t)biA * DIM + quad * 8;
            f32x4 c0 = *(const f32x4*)(cp);
            f32x4 c1 = *(const f32x4*)(cp + 4);
            f32x4 c2 = *(const f32x4*)(cp + 32);
            f32x4 c3 = *(const f32x4*)(cp + 36);
#pragma unroll
            for (int j = 0; j < 4; ++j) {
                float v0 = fmaf(RISCALE, (float)tlA0[j],   (float)thA0[j])   - c0[j];
                float v1 = fmaf(RISCALE, (float)tlA0[j+4], (float)thA0[j+4]) - c1[j];
                float v2 = fmaf(RISCALE, (float)tlA1[j],   (float)thA1[j])   - c2[j];
                float v3 = fmaf(RISCALE, (float)tlA1[j+4], (float)thA1[j+4]) - c3[j];
                ls = fmaf(v0, v0, ls); ls = fmaf(v1, v1, ls);
                ls = fmaf(v2, v2, ls); ls = fmaf(v3, v3, ls);
                SPLIT3(v0, thA0[j],   tlA0[j],   tsA0[j]);
                SPLIT3(v1, thA0[j+4], tlA0[j+4], tsA0[j+4]);
                SPLIT3(v2, thA1[j],   tlA1[j],   tsA1[j]);
                SPLIT3(v3, thA1[j+4], tlA1[j+4], tsA1[j+4]);
            }
        }
        {
            const float* cp = cfq + (size_t)biB * DIM + quad * 8;
            f32x4 c0 = *(const f32x4*)(cp);
            f32x4 c1 = *(const f32x4*)(cp + 4);
            f32x4 c2 = *(const f32x4*)(cp + 32);
            f32x4 c3 = *(const f32x4*)(cp + 36);
#pragma unroll
            for (int j = 0; j < 4; ++j) {
                float v0 = fmaf(RISCALE, (float)tlB0[j],   (float)thB0[j])   - c0[j];
                float v1 = fmaf(RISCALE, (float)tlB0[j+4], (float)thB0[j+4]) - c1[j];
                float v2 = fmaf(RISCALE, (float)tlB1[j],   (float)thB1[j])   - c2[j];
                float v3 = fmaf(RISCALE, (float)tlB1[j+4], (float)thB1[j+4]) - c3[j];
                ls = fmaf(v0, v0, ls); ls = fmaf(v1, v1, ls);
                ls = fmaf(v2, v2, ls); ls = fmaf(v3, v3, ls);
                SPLIT3(v0, thB0[j],   tlB0[j],   tsB0[j]);
                SPLIT3(v1, thB0[j+4], tlB0[j+4], tsB0[j+4]);
                SPLIT3(v2, thB1[j],   tlB1[j],   tsB1[j]);
                SPLIT3(v3, thB1[j+4], tlB1[j+4], tsB1[j+4]);
            }
        }
#pragma unroll
        for (int mask = 1; mask <= 32; mask <<= 1) ls += __shfl_xor(ls, mask, 64);
        if (lane == 0)
            atomicAdd(out + (size_t)N_TOK * DIM + (size_t)N_TOK * QS + q,
                      ls * (1.0f / ((float)N_TOK * (float)DIM)));
    }

    // xq = x - r_final (reconstruct final residual from limbs)
    {
        const size_t ra = (size_t)tokA * DIM + quad * 8;
        const size_t rb = (size_t)tokB * DIM + quad * 8;
        f32x4 a0 = __builtin_nontemporal_load((const f32x4*)(x + ra));
        f32x4 a1 = __builtin_nontemporal_load((const f32x4*)(x + ra + 4));
        f32x4 a2 = __builtin_nontemporal_load((const f32x4*)(x + ra + 32));
        f32x4 a3 = __builtin_nontemporal_load((const f32x4*)(x + ra + 36));
        f32x4 b0 = __builtin_nontemporal_load((const f32x4*)(x + rb));
        f32x4 b1 = __builtin_nontemporal_load((const f32x4*)(x + rb + 4));
        f32x4 b2 = __builtin_nontemporal_load((const f32x4*)(x + rb + 32));
        f32x4 b3 = __builtin_nontemporal_load((const f32x4*)(x + rb + 36));
#pragma unroll
        for (int j = 0; j < 4; ++j) {
            a0[j] -= fmaf(RISCALE, (float)tlA0[j],   (float)thA0[j]);
            a1[j] -= fmaf(RISCALE, (float)tlA0[j+4], (float)thA0[j+4]);
            a2[j] -= fmaf(RISCALE, (float)tlA1[j],   (float)thA1[j]);
            a3[j] -= fmaf(RISCALE, (float)tlA1[j+4], (float)thA1[j+4]);
            b0[j] -= fmaf(RISCALE, (float)tlB0[j],   (float)thB0[j]);
            b1[j] -= fmaf(RISCALE, (float)tlB0[j+4], (float)thB0[j+4]);
            b2[j] -= fmaf(RISCALE, (float)tlB1[j],   (float)thB1[j]);
            b3[j] -= fmaf(RISCALE, (float)tlB1[j+4], (float)thB1[j+4]);
        }
        __builtin_nontemporal_store(a0, (f32x4*)(out + ra));
        __builtin_nontemporal_store(a1, (f32x4*)(out + ra + 4));
        __builtin_nontemporal_store(a2, (f32x4*)(out + ra + 32));
        __builtin_nontemporal_store(a3, (f32x4*)(out + ra + 36));
        __builtin_nontemporal_store(b0, (f32x4*)(out + rb));
        __builtin_nontemporal_store(b1, (f32x4*)(out + rb + 4));
        __builtin_nontemporal_store(b2, (f32x4*)(out + rb + 32));
        __builtin_nontemporal_store(b3, (f32x4*)(out + rb + 36));
    }
#undef COMPUTE
}

extern "C" void kernel_launch(void* const* d_in, const int* in_sizes, int n_in,
                              void* d_out, int out_size, void* d_ws, size_t ws_size,
                              hipStream_t stream) {
    const float* x   = (const float*)d_in[0];   // (N, D)
    const float* cb  = (const float*)d_in[1];   // (Q, K, D)
    float*       out = (float*)d_out;           // [xq | indices | losses]
    char*        ws  = (char*)d_ws;

    _Float16* F    = (_Float16*)ws;                       // 2 MB fragment-ordered limbs
    float*    dc2s = (float*)(ws + 2097152);              // 32 KB

    hipMemsetAsync(out + (size_t)N_TOK * DIM + (size_t)N_TOK * QS, 0,
                   QS * sizeof(float), stream);

    conv_kernel<<<512, 256, 0, stream>>>(cb, F);
    dc2_kernel<<<(QS * KS + 255) / 256, 256, 0, stream>>>(cb, dc2s);
    rvq_mfma_kernel<<<N_TOK / 128, 256, 0, stream>>>(x, cb, F, dc2s, out);
}